// Round 8
// baseline (285.267 us; speedup 1.0000x reference)
//
#include <hip/hip_runtime.h>

#define ROWS_TOTAL 131072
#define XST 232             // g_xb row stride in bf16 elements (464 B)

typedef float f32x4 __attribute__((ext_vector_type(4)));
typedef short s16x8 __attribute__((ext_vector_type(8)));

// W pre-arranged, per 112-col group, fragment-linear:
//   byte = cg*50176 + kk*7168 + ks*1792 + col112*16 + e
__device__ unsigned short g_Wb2[7 * 25088];
// x patchified, bf16, row stride 232 ushorts (zero-padded k = 196..231)
__device__ unsigned short g_xb[(size_t)ROWS_TOTAL * XST];

__device__ __forceinline__ unsigned short f2bf(float f) {
    unsigned int u = __builtin_bit_cast(unsigned int, f);
    u += 0x7fffu + ((u >> 16) & 1u);        // round-to-nearest-even
    return (unsigned short)(u >> 16);
}

__global__ void prep_w(const float* __restrict__ W) {
    int t = blockIdx.x * 256 + threadIdx.x;   // 784 cols * 56 k-quads
    if (t >= 784 * 56) return;
    int col = t / 56;
    int k0  = (t - col * 56) * 4;
    uint2 pk;
    if (k0 < 196) {
        f32x4 d = *(const f32x4*)(W + col * 196 + k0);
        pk.x = (unsigned int)f2bf(d[0]) | ((unsigned int)f2bf(d[1]) << 16);
        pk.y = (unsigned int)f2bf(d[2]) | ((unsigned int)f2bf(d[3]) << 16);
    } else {
        pk.x = 0u; pk.y = 0u;
    }
    int group = col / 112, col112 = col - group * 112;
    int kk = k0 >> 5, rem = k0 & 31, ks = rem >> 3, e0 = rem & 7;
    size_t di = (size_t)((((group * 7 + kk) * 4 + ks) * 112) + col112) * 8 + e0;
    *(uint2*)(g_Wb2 + di) = pk;
}

// patchify: x[32768,28,28] fp32 -> g_xb[131072][232] bf16 (zero-padded)
__global__ void prep_x(const float* __restrict__ x) {
    const int NV = ROWS_TOTAL / 4 * 784 / 4;            // 6,422,528 float4s
    const f32x4* xv = (const f32x4*)x;
    for (int v = blockIdx.x * 256 + threadIdx.x; v < NV; v += gridDim.x * 256) {
        f32x4 d = xv[v];
        int F   = v * 4;
        int img = F / 784;
        int rem = F - img * 784;
        int h   = rem / 28;
        int w0  = rem - h * 28;          // in {0,4,...,24}
        int ph  = h / 14;
        int r   = h - ph * 14;
        int rowb = img * 4 + ph * 2;
        #pragma unroll
        for (int p = 0; p < 2; ++p) {
            int w  = w0 + 2 * p;         // even => bf16 pair stays inside one patch
            int pw = (w >= 14) ? 1 : 0;
            int c  = w - pw * 14;
            int row = rowb + pw;
            unsigned int pack = (unsigned int)f2bf(d[2 * p]) |
                                ((unsigned int)f2bf(d[2 * p + 1]) << 16);
            *(unsigned int*)((char*)g_xb + (size_t)row * (XST * 2) + (r * 14 + c) * 2) = pack;
        }
    }
    for (int t = blockIdx.x * 256 + threadIdx.x; t < ROWS_TOTAL * 9; t += gridDim.x * 256) {
        int row = t / 9;
        int j   = t - row * 9;
        *(uint2*)((char*)g_xb + (size_t)row * (XST * 2) + 392 + j * 8) = (uint2){0u, 0u};
    }
}

__device__ __forceinline__ void gload_lds16(void* lds, const void* g) {
    __builtin_amdgcn_global_load_lds(
        (const __attribute__((address_space(1))) unsigned int*)g,
        (__attribute__((address_space(3))) unsigned int*)lds, 16, 0, 0);
}

// Block: 128 out rows x 112 out cols; 4 waves, each 32 rows (2 m-frags) x 112 cols.
// W read straight from global (L1/L2-resident, coalesced 4x256B per load);
// only x staged in LDS (58 KiB linear DMA -> 2 blocks/CU). One barrier per block.
// Grid is cg-major so co-resident blocks share the same 50 KB W-group.
__global__ __launch_bounds__(256, 2)
void patch_linear_mfma(const float* __restrict__ blin,
                       float* __restrict__ out) {
    __shared__ __align__(16) char sX[58 * 1024];   // 128 rows x 464 B

    const int tid  = threadIdx.x;
    const int l    = tid & 63;
    const int wv   = tid >> 6;          // 0..3
    const int lrow = l & 15;
    const int lk   = l >> 4;

    const int cg = blockIdx.x >> 10;    // col group (112 cols), 0..6
    const int rg = blockIdx.x & 1023;   // row group (128 rows)

    // ---- stage x rows: 58 x 1 KiB linear async DMA ----
    const char* xsrc = (const char*)g_xb + (size_t)rg * 59392 + l * 16;
    #pragma unroll
    for (int c = 0; c < 15; ++c) {
        int ch = wv + c * 4;
        if (ch < 58) gload_lds16(sX + ch * 1024, xsrc + ch * 1024);
    }

    // acc init = bias: acc[m][n][j] = blin[cg*112 + n*16 + lk*4 + j]
    f32x4 acc[2][7];
    #pragma unroll
    for (int n = 0; n < 7; ++n) {
        f32x4 b = *(const f32x4*)(blin + cg * 112 + n * 16 + lk * 4);
        acc[0][n] = b;
        acc[1][n] = b;
    }

    __syncthreads();   // drains sX staging; the only barrier

    const char* wbase = (const char*)g_Wb2 + cg * 50176 + lk * 1792 + lrow * 16;
    const char* xb    = sX + (wv * 32 + lrow) * 464 + lk * 16;

    #pragma unroll
    for (int kk = 0; kk < 7; ++kk) {
        s16x8 xf0 = *(const s16x8*)(xb + kk * 64);
        s16x8 xf1 = *(const s16x8*)(xb + 16 * 464 + kk * 64);
        #pragma unroll
        for (int n = 0; n < 7; ++n) {
            s16x8 wf = *(const s16x8*)(wbase + kk * 7168 + n * 256);
            acc[0][n] = __builtin_amdgcn_mfma_f32_16x16x32_bf16(wf, xf0, acc[0][n], 0, 0, 0);
            acc[1][n] = __builtin_amdgcn_mfma_f32_16x16x32_bf16(wf, xf1, acc[1][n], 0, 0, 0);
        }
    }

    // ---- store: 14 dwordx4/lane; each (row, n) is a full aligned 64-B sector ----
    float* orow = out + (size_t)(rg * 128 + wv * 32 + lrow) * 784 + cg * 112 + lk * 4;
    #pragma unroll
    for (int m = 0; m < 2; ++m)
        #pragma unroll
        for (int n = 0; n < 7; ++n)
            *(f32x4*)(orow + m * 16 * 784 + n * 16) = acc[m][n];
}

extern "C" void kernel_launch(void* const* d_in, const int* in_sizes, int n_in,
                              void* d_out, int out_size, void* d_ws, size_t ws_size,
                              hipStream_t stream) {
    const float* x    = (const float*)d_in[0];   // [32768,1,28,28]
    const float* Wlin = (const float*)d_in[1];   // [784,196]
    const float* blin = (const float*)d_in[2];   // [784]
    float* out = (float*)d_out;                  // [32768,4,784]

    prep_w<<<(784 * 56 + 255) / 256, 256, 0, stream>>>(Wlin);
    prep_x<<<4096, 256, 0, stream>>>(x);

    dim3 grid(7 * 1024);                         // cg-major, 7168 blocks
    dim3 block(256);
    patch_linear_mfma<<<grid, block, 0, stream>>>(blin, out);
}

// Round 9
// 220.192 us; speedup vs baseline: 1.2955x; 1.2955x over previous
//
#include <hip/hip_runtime.h>

#define ROWS_TOTAL 131072
#define XST 232             // g_xb row stride in bf16 elements (464 B)

typedef float f32x4 __attribute__((ext_vector_type(4)));
typedef short s16x8 __attribute__((ext_vector_type(8)));

// W pre-arranged, per 112-col group, fragment-linear:
//   byte = cg*50176 + kk*7168 + ks*1792 + col112*16 + e
__device__ unsigned short g_Wb2[7 * 25088];
// x patchified, bf16, row stride 232 ushorts (zero-padded k = 196..231)
__device__ unsigned short g_xb[(size_t)ROWS_TOTAL * XST];

__device__ __forceinline__ unsigned short f2bf(float f) {
    unsigned int u = __builtin_bit_cast(unsigned int, f);
    u += 0x7fffu + ((u >> 16) & 1u);        // round-to-nearest-even
    return (unsigned short)(u >> 16);
}

__global__ void prep_w(const float* __restrict__ W) {
    int t = blockIdx.x * 256 + threadIdx.x;   // 784 cols * 56 k-quads
    if (t >= 784 * 56) return;
    int col = t / 56;
    int k0  = (t - col * 56) * 4;
    uint2 pk;
    if (k0 < 196) {
        f32x4 d = *(const f32x4*)(W + col * 196 + k0);
        pk.x = (unsigned int)f2bf(d[0]) | ((unsigned int)f2bf(d[1]) << 16);
        pk.y = (unsigned int)f2bf(d[2]) | ((unsigned int)f2bf(d[3]) << 16);
    } else {
        pk.x = 0u; pk.y = 0u;
    }
    int group = col / 112, col112 = col - group * 112;
    int kk = k0 >> 5, rem = k0 & 31, ks = rem >> 3, e0 = rem & 7;
    size_t di = (size_t)((((group * 7 + kk) * 4 + ks) * 112) + col112) * 8 + e0;
    *(uint2*)(g_Wb2 + di) = pk;
}

// patchify: x[32768,28,28] fp32 -> g_xb[131072][232] bf16 (zero-padded)
__global__ void prep_x(const float* __restrict__ x) {
    const int NV = ROWS_TOTAL / 4 * 784 / 4;            // 6,422,528 float4s
    const f32x4* xv = (const f32x4*)x;
    for (int v = blockIdx.x * 256 + threadIdx.x; v < NV; v += gridDim.x * 256) {
        f32x4 d = xv[v];
        int F   = v * 4;
        int img = F / 784;
        int rem = F - img * 784;
        int h   = rem / 28;
        int w0  = rem - h * 28;          // in {0,4,...,24}
        int ph  = h / 14;
        int r   = h - ph * 14;
        int rowb = img * 4 + ph * 2;
        #pragma unroll
        for (int p = 0; p < 2; ++p) {
            int w  = w0 + 2 * p;         // even => bf16 pair stays inside one patch
            int pw = (w >= 14) ? 1 : 0;
            int c  = w - pw * 14;
            int row = rowb + pw;
            unsigned int pack = (unsigned int)f2bf(d[2 * p]) |
                                ((unsigned int)f2bf(d[2 * p + 1]) << 16);
            *(unsigned int*)((char*)g_xb + (size_t)row * (XST * 2) + (r * 14 + c) * 2) = pack;
        }
    }
    for (int t = blockIdx.x * 256 + threadIdx.x; t < ROWS_TOTAL * 9; t += gridDim.x * 256) {
        int row = t / 9;
        int j   = t - row * 9;
        *(uint2*)((char*)g_xb + (size_t)row * (XST * 2) + 392 + j * 8) = (uint2){0u, 0u};
    }
}

__device__ __forceinline__ void gload_lds16(void* lds, const void* g) {
    __builtin_amdgcn_global_load_lds(
        (const __attribute__((address_space(1))) unsigned int*)g,
        (__attribute__((address_space(3))) unsigned int*)lds, 16, 0, 0);
}

// Block: 64 out rows x 112 out cols; 4 waves, each 16 rows x 112 cols.
// W fragments straight from global (coalesced 4x256B, L1/L2-resident);
// x staged in LDS (29 KiB linear DMA -> 4 blocks/CU). One barrier per block.
// XCD swizzle groups the 7 cg-siblings of each row-group consecutively on one
// XCD: partial 128B out-lines meet in the same L2 (write-combine) and the
// shared x-chunk is fetched once per XCD.
__global__ __launch_bounds__(256, 4)
void patch_linear_mfma(const float* __restrict__ blin,
                       float* __restrict__ out) {
    __shared__ __align__(16) char sX[29 * 1024];   // 64 rows x 464 B

    const int tid  = threadIdx.x;
    const int l    = tid & 63;
    const int wv   = tid >> 6;          // 0..3
    const int lrow = l & 15;
    const int lk   = l >> 4;

    // decode swizzled id: g = r8 + 8*(q*7 + cg), rg = q*8 + r8  (bijective)
    const int g  = blockIdx.x;
    const int r8 = g & 7;
    const int t  = g >> 3;
    const int q  = t / 7;
    const int cg = t - q * 7;           // col group (112 cols), 0..6
    const int rg = q * 8 + r8;          // row group (64 rows),  0..2047

    // ---- stage x rows: 29 x 1 KiB linear async DMA ----
    const char* xsrc = (const char*)g_xb + (size_t)rg * 29696 + l * 16;
    #pragma unroll
    for (int c = 0; c < 8; ++c) {
        int ch = wv + c * 4;
        if (ch < 29) gload_lds16(sX + ch * 1024, xsrc + ch * 1024);
    }

    // acc init = bias: acc[n][j] = blin[cg*112 + n*16 + lk*4 + j]
    f32x4 acc[7];
    #pragma unroll
    for (int n = 0; n < 7; ++n)
        acc[n] = *(const f32x4*)(blin + cg * 112 + n * 16 + lk * 4);

    __syncthreads();   // drains sX staging; the only barrier

    const char* wbase = (const char*)g_Wb2 + cg * 50176 + lk * 1792 + lrow * 16;
    const char* xb    = sX + (wv * 16 + lrow) * 464 + lk * 16;

    #pragma unroll
    for (int kk = 0; kk < 7; ++kk) {
        s16x8 xf = *(const s16x8*)(xb + kk * 64);
        #pragma unroll
        for (int n = 0; n < 7; ++n) {
            s16x8 wf = *(const s16x8*)(wbase + kk * 7168 + n * 256);
            acc[n] = __builtin_amdgcn_mfma_f32_16x16x32_bf16(wf, xf, acc[n], 0, 0, 0);
        }
    }

    // ---- store: 7 dwordx4/lane; each (row, n) is a full aligned 64-B sector ----
    float* orow = out + (size_t)(rg * 64 + wv * 16 + lrow) * 784 + cg * 112 + lk * 4;
    #pragma unroll
    for (int n = 0; n < 7; ++n)
        *(f32x4*)(orow + n * 16) = acc[n];
}

extern "C" void kernel_launch(void* const* d_in, const int* in_sizes, int n_in,
                              void* d_out, int out_size, void* d_ws, size_t ws_size,
                              hipStream_t stream) {
    const float* x    = (const float*)d_in[0];   // [32768,1,28,28]
    const float* Wlin = (const float*)d_in[1];   // [784,196]
    const float* blin = (const float*)d_in[2];   // [784]
    float* out = (float*)d_out;                  // [32768,4,784]

    prep_w<<<(784 * 56 + 255) / 256, 256, 0, stream>>>(Wlin);
    prep_x<<<4096, 256, 0, stream>>>(x);

    dim3 grid(2048 * 7);                         // 14336 blocks, XCD-grouped swizzle
    dim3 block(256);
    patch_linear_mfma<<<grid, block, 0, stream>>>(blin, out);
}

// Round 10
// 180.472 us; speedup vs baseline: 1.5807x; 1.2201x over previous
//
#include <hip/hip_runtime.h>

#define ROWS_TOTAL 131072
#define XST 200             // g_xb/sX row stride in bf16 elements (400 B)

typedef float f32x4 __attribute__((ext_vector_type(4)));
typedef short s16x8 __attribute__((ext_vector_type(8)));

// W fragment-linear, per 112-col group:
//   ushort idx = ((cg*7 + kk)*112 + col112)*32 + ks*8 + e   (zero-padded k>=196)
__device__ unsigned short g_Wb3[7 * 7 * 112 * 32];          // 351 KB
// x patchified, bf16, row stride 200 ushorts (zero-padded k = 196..199)
__device__ unsigned short g_xb[(size_t)ROWS_TOTAL * XST];   // 52.4 MB

__device__ __forceinline__ unsigned short f2bf(float f) {
    unsigned int u = __builtin_bit_cast(unsigned int, f);
    u += 0x7fffu + ((u >> 16) & 1u);        // round-to-nearest-even
    return (unsigned short)(u >> 16);
}

__global__ void prep_w(const float* __restrict__ W) {
    int t = blockIdx.x * 256 + threadIdx.x;   // 784 cols * 56 k-quads
    if (t >= 784 * 56) return;
    int col = t / 56;
    int k0  = (t - col * 56) * 4;
    uint2 pk;
    if (k0 < 196) {
        f32x4 d = *(const f32x4*)(W + col * 196 + k0);
        pk.x = (unsigned int)f2bf(d[0]) | ((unsigned int)f2bf(d[1]) << 16);
        pk.y = (unsigned int)f2bf(d[2]) | ((unsigned int)f2bf(d[3]) << 16);
    } else {
        pk.x = 0u; pk.y = 0u;
    }
    int cg = col / 112, col112 = col - cg * 112;
    int kk = k0 >> 5, rem = k0 & 31, ks = rem >> 3, e0 = rem & 7;
    size_t di = (size_t)(((cg * 7 + kk) * 112 + col112)) * 32 + ks * 8 + e0;
    *(uint2*)(g_Wb3 + di) = pk;
}

// patchify: x[32768,28,28] fp32 -> g_xb[131072][200] bf16 (zero-padded)
__global__ void prep_x(const float* __restrict__ x) {
    const int NV = ROWS_TOTAL / 4 * 784 / 4;            // 6,422,528 float4s
    const f32x4* xv = (const f32x4*)x;
    for (int v = blockIdx.x * 256 + threadIdx.x; v < NV; v += gridDim.x * 256) {
        f32x4 d = xv[v];
        int F   = v * 4;
        int img = F / 784;
        int rem = F - img * 784;
        int h   = rem / 28;
        int w0  = rem - h * 28;          // in {0,4,...,24}
        int ph  = h / 14;
        int r   = h - ph * 14;
        int rowb = img * 4 + ph * 2;
        #pragma unroll
        for (int p = 0; p < 2; ++p) {
            int w  = w0 + 2 * p;         // even => bf16 pair stays inside one patch
            int pw = (w >= 14) ? 1 : 0;
            int c  = w - pw * 14;
            int row = rowb + pw;
            unsigned int pack = (unsigned int)f2bf(d[2 * p]) |
                                ((unsigned int)f2bf(d[2 * p + 1]) << 16);
            *(unsigned int*)((char*)g_xb + (size_t)row * (XST * 2) + (r * 14 + c) * 2) = pack;
        }
    }
    for (int row = blockIdx.x * 256 + threadIdx.x; row < ROWS_TOTAL; row += gridDim.x * 256) {
        *(uint2*)((char*)g_xb + (size_t)row * (XST * 2) + 392) = (uint2){0u, 0u};
    }
}

__device__ __forceinline__ void gload_lds16(void* lds, const void* g) {
    __builtin_amdgcn_global_load_lds(
        (const __attribute__((address_space(1))) unsigned int*)g,
        (__attribute__((address_space(3))) unsigned int*)lds, 16, 0, 0);
}

// Block: 256 out rows x ALL 784 cols (one contiguous 802,816-B output region).
// 8 waves; wave = 32 rows (2 m-frags) x 112 cols. x staged ONCE in sX (100 KiB);
// W col-group re-staged per phase in sW (49 KiB, single-buffered). All LDS
// reads conflict-free; 13 barriers/block total.
__global__ __launch_bounds__(512, 2)
void patch_linear_mfma(const float* __restrict__ blin,
                       float* __restrict__ out) {
    __shared__ __align__(16) char sX[100 * 1024];   // 256 rows x 400 B
    __shared__ __align__(16) char sW[49 * 1024];    // [kk][col112][ks][16B]

    const int tid  = threadIdx.x;
    const int l    = tid & 63;
    const int wv   = tid >> 6;          // 0..7
    const int lrow = l & 15;
    const int lk   = l >> 4;

    const int blk = blockIdx.x;

    // ---- stage x once: 100 x 1 KiB, and W group 0: 49 x 1 KiB (async DMA) ----
    const char* xsrc = (const char*)g_xb + (size_t)blk * 102400 + l * 16;
    #pragma unroll
    for (int c = 0; c < 13; ++c) {
        int ch = wv + c * 8;
        if (ch < 100) gload_lds16(sX + ch * 1024, xsrc + ch * 1024);
    }
    const char* wsrc = (const char*)g_Wb3 + l * 16;
    #pragma unroll
    for (int c = 0; c < 7; ++c) {
        int ch = wv + c * 8;
        if (ch < 49) gload_lds16(sW + ch * 1024, wsrc + ch * 1024);
    }

    const char* xb = sX + (wv * 32 + lrow) * 400 + lk * 16;
    const char* wb = sW + lrow * 64 + lk * 16;
    float* orow = out + ((size_t)blk * 256 + wv * 32 + lrow) * 784 + lk * 4;

    const s16x8 zero8 = {0, 0, 0, 0, 0, 0, 0, 0};
    const bool  sel   = (lk == 0);
    const int   toff  = sel ? 384 : 0;   // k=192 slice for lk==0, safe addr otherwise

    for (int cg = 0; cg < 7; ++cg) {
        __syncthreads();   // staged data (sX+sW[cg]) visible; drains DMA vmcnt

        // acc init = bias: acc[m][n][j] = blin[cg*112 + n*16 + lk*4 + j]
        f32x4 acc[2][7];
        #pragma unroll
        for (int n = 0; n < 7; ++n) {
            f32x4 b = *(const f32x4*)(blin + cg * 112 + n * 16 + lk * 4);
            acc[0][n] = b;
            acc[1][n] = b;
        }

        // full K-steps kk = 0..5
        #pragma unroll
        for (int kk = 0; kk < 6; ++kk) {
            s16x8 xf0 = *(const s16x8*)(xb + kk * 64);
            s16x8 xf1 = *(const s16x8*)(xb + 6400 + kk * 64);   // +16 rows
            #pragma unroll
            for (int n = 0; n < 7; ++n) {
                s16x8 wf = *(const s16x8*)(wb + kk * 7168 + n * 1024);
                acc[0][n] = __builtin_amdgcn_mfma_f32_16x16x32_bf16(wf, xf0, acc[0][n], 0, 0, 0);
                acc[1][n] = __builtin_amdgcn_mfma_f32_16x16x32_bf16(wf, xf1, acc[1][n], 0, 0, 0);
            }
        }
        // K tail kk=6: x masked to lk==0 (k192-195 real + 196-199 zeros); W zero-padded
        {
            s16x8 t0 = *(const s16x8*)(xb + toff);
            s16x8 t1 = *(const s16x8*)(xb + 6400 + toff);
            s16x8 xf0 = sel ? t0 : zero8;
            s16x8 xf1 = sel ? t1 : zero8;
            #pragma unroll
            for (int n = 0; n < 7; ++n) {
                s16x8 wf = *(const s16x8*)(wb + 6 * 7168 + n * 1024);
                acc[0][n] = __builtin_amdgcn_mfma_f32_16x16x32_bf16(wf, xf0, acc[0][n], 0, 0, 0);
                acc[1][n] = __builtin_amdgcn_mfma_f32_16x16x32_bf16(wf, xf1, acc[1][n], 0, 0, 0);
            }
        }

        // store this col-group: 14 dwordx4/lane, full 64-B sectors
        #pragma unroll
        for (int m = 0; m < 2; ++m)
            #pragma unroll
            for (int n = 0; n < 7; ++n)
                *(f32x4*)(orow + m * 16 * 784 + cg * 112 + n * 16) = acc[m][n];

        // re-stage sW for next col-group
        if (cg < 6) {
            __syncthreads();   // all waves done reading sW[cg]
            const char* ws = (const char*)g_Wb3 + (size_t)(cg + 1) * 50176 + l * 16;
            #pragma unroll
            for (int c = 0; c < 7; ++c) {
                int ch = wv + c * 8;
                if (ch < 49) gload_lds16(sW + ch * 1024, ws + ch * 1024);
            }
        }
    }
}

extern "C" void kernel_launch(void* const* d_in, const int* in_sizes, int n_in,
                              void* d_out, int out_size, void* d_ws, size_t ws_size,
                              hipStream_t stream) {
    const float* x    = (const float*)d_in[0];   // [32768,1,28,28]
    const float* Wlin = (const float*)d_in[1];   // [784,196]
    const float* blin = (const float*)d_in[2];   // [784]
    float* out = (float*)d_out;                  // [32768,4,784]

    prep_w<<<(784 * 56 + 255) / 256, 256, 0, stream>>>(Wlin);
    prep_x<<<4096, 256, 0, stream>>>(x);

    dim3 grid(ROWS_TOTAL / 256);                 // 512 blocks, each a contiguous region
    dim3 block(512);
    patch_linear_mfma<<<grid, block, 0, stream>>>(blin, out);
}

// Round 11
// 170.271 us; speedup vs baseline: 1.6754x; 1.0599x over previous
//
#include <hip/hip_runtime.h>

#define ROWS_TOTAL 131072
#define XST 224             // g_xb row stride in bf16 elements (448 B, zero-padded)

typedef float f32x4 __attribute__((ext_vector_type(4)));
typedef short s16x8 __attribute__((ext_vector_type(8)));

// W fragment-linear, per 112-col group:
//   ushort idx = ((cg*7 + kk)*112 + col112)*32 + ks*8 + e   (zero-padded k>=196)
__device__ unsigned short g_Wb3[7 * 7 * 112 * 32];          // 351 KB
// x patchified, bf16, row stride 224 ushorts (zero-padded k = 196..223)
__device__ unsigned short g_xb[(size_t)ROWS_TOTAL * XST];   // 58.7 MB

__device__ __forceinline__ unsigned short f2bf(float f) {
    unsigned int u = __builtin_bit_cast(unsigned int, f);
    u += 0x7fffu + ((u >> 16) & 1u);        // round-to-nearest-even
    return (unsigned short)(u >> 16);
}

__global__ void prep_w(const float* __restrict__ W) {
    int t = blockIdx.x * 256 + threadIdx.x;   // 784 cols * 56 k-quads
    if (t >= 784 * 56) return;
    int col = t / 56;
    int k0  = (t - col * 56) * 4;
    uint2 pk;
    if (k0 < 196) {
        f32x4 d = *(const f32x4*)(W + col * 196 + k0);
        pk.x = (unsigned int)f2bf(d[0]) | ((unsigned int)f2bf(d[1]) << 16);
        pk.y = (unsigned int)f2bf(d[2]) | ((unsigned int)f2bf(d[3]) << 16);
    } else {
        pk.x = 0u; pk.y = 0u;
    }
    int cg = col / 112, col112 = col - cg * 112;
    int kk = k0 >> 5, rem = k0 & 31, ks = rem >> 3, e0 = rem & 7;
    size_t di = (size_t)(((cg * 7 + kk) * 112 + col112)) * 32 + ks * 8 + e0;
    *(uint2*)(g_Wb3 + di) = pk;
}

// patchify: x[32768,28,28] fp32 -> g_xb[131072][224] bf16 (zero-padded)
__global__ void prep_x(const float* __restrict__ x) {
    const int NV = ROWS_TOTAL / 4 * 784 / 4;            // 6,422,528 float4s
    const f32x4* xv = (const f32x4*)x;
    for (int v = blockIdx.x * 256 + threadIdx.x; v < NV; v += gridDim.x * 256) {
        f32x4 d = xv[v];
        int F   = v * 4;
        int img = F / 784;
        int rem = F - img * 784;
        int h   = rem / 28;
        int w0  = rem - h * 28;          // in {0,4,...,24}
        int ph  = h / 14;
        int r   = h - ph * 14;
        int rowb = img * 4 + ph * 2;
        #pragma unroll
        for (int p = 0; p < 2; ++p) {
            int w  = w0 + 2 * p;         // even => bf16 pair stays inside one patch
            int pw = (w >= 14) ? 1 : 0;
            int c  = w - pw * 14;
            int row = rowb + pw;
            unsigned int pack = (unsigned int)f2bf(d[2 * p]) |
                                ((unsigned int)f2bf(d[2 * p + 1]) << 16);
            *(unsigned int*)((char*)g_xb + (size_t)row * (XST * 2) + (r * 14 + c) * 2) = pack;
        }
    }
    // zero pad k = 196..223 for every row: 7 uint2 per row (bytes 392..447)
    for (int t = blockIdx.x * 256 + threadIdx.x; t < ROWS_TOTAL * 7; t += gridDim.x * 256) {
        int row = t / 7;
        int j   = t - row * 7;
        *(uint2*)((char*)g_xb + (size_t)row * (XST * 2) + 392 + j * 8) = (uint2){0u, 0u};
    }
}

__device__ __forceinline__ void gload_lds16(void* lds, const void* g) {
    __builtin_amdgcn_global_load_lds(
        (const __attribute__((address_space(1))) unsigned int*)g,
        (__attribute__((address_space(3))) unsigned int*)lds, 16, 0, 0);
}

// Block: 128 out rows x 112 out cols; 4 waves, each 32 rows (2 m-frags).
// x fragments loaded straight to REGISTERS (no sX, no K-tail masking);
// W group staged once in LDS (49 KiB -> 3 blocks/CU). ONE barrier per block.
// XCD swizzle: 7 cg-siblings of a row-group run consecutively on one XCD
// (x L2-hot, output 128B lines write-combine in one L2).
__global__ __launch_bounds__(256, 3)
void patch_linear_mfma(const float* __restrict__ blin,
                       float* __restrict__ out) {
    __shared__ __align__(16) char sW[49 * 1024];   // [kk][col112][ks][16B]

    const int tid  = threadIdx.x;
    const int l    = tid & 63;
    const int wv   = tid >> 6;          // 0..3
    const int lrow = l & 15;
    const int lk   = l >> 4;

    // bijective swizzle: g = r8 + 8*(q*7 + cg); rg = q*8 + r8
    const int g  = blockIdx.x;
    const int r8 = g & 7;
    const int t  = g >> 3;
    const int q  = t / 7;
    const int cg = t - q * 7;           // col group (112 cols), 0..6
    const int rg = q * 8 + r8;          // row group (128 rows), 0..1023

    // ---- stage W group: 49 x 1 KiB linear async DMA ----
    const char* wsrc = (const char*)g_Wb3 + (size_t)cg * 50176 + l * 16;
    #pragma unroll
    for (int c = 0; c < 13; ++c) {
        int ch = wv + c * 4;
        if (ch < 49) gload_lds16(sW + ch * 1024, wsrc + ch * 1024);
    }

    // ---- x fragments -> registers (overlaps the DMA) ----
    // per load: 16 rows x 64 B full segments, 100% txn efficiency
    const char* xb = (const char*)g_xb +
                     ((size_t)rg * 128 + wv * 32 + lrow) * 448 + lk * 16;
    s16x8 xf[2][7];
    #pragma unroll
    for (int m = 0; m < 2; ++m)
        #pragma unroll
        for (int kk = 0; kk < 7; ++kk)
            xf[m][kk] = *(const s16x8*)(xb + m * (16 * 448) + kk * 64);

    // acc init = bias: acc[m][n][j] = blin[cg*112 + n*16 + lk*4 + j]
    f32x4 acc[2][7];
    #pragma unroll
    for (int n = 0; n < 7; ++n) {
        f32x4 b = *(const f32x4*)(blin + cg * 112 + n * 16 + lk * 4);
        acc[0][n] = b;
        acc[1][n] = b;
    }

    __syncthreads();   // drains W DMA (+ xf loads); the only barrier

    const char* wb = sW + lrow * 64 + lk * 16;
    #pragma unroll
    for (int kk = 0; kk < 7; ++kk) {
        #pragma unroll
        for (int n = 0; n < 7; ++n) {
            s16x8 wf = *(const s16x8*)(wb + kk * 7168 + n * 1024);
            acc[0][n] = __builtin_amdgcn_mfma_f32_16x16x32_bf16(wf, xf[0][kk], acc[0][n], 0, 0, 0);
            acc[1][n] = __builtin_amdgcn_mfma_f32_16x16x32_bf16(wf, xf[1][kk], acc[1][n], 0, 0, 0);
        }
    }

    // ---- store: 14 dwordx4/lane; dense 128x448B region per block ----
    float* orow = out + ((size_t)rg * 128 + wv * 32 + lrow) * 784 + cg * 112 + lk * 4;
    #pragma unroll
    for (int m = 0; m < 2; ++m)
        #pragma unroll
        for (int n = 0; n < 7; ++n)
            *(f32x4*)(orow + m * (16 * 784) + n * 16) = acc[m][n];
}

extern "C" void kernel_launch(void* const* d_in, const int* in_sizes, int n_in,
                              void* d_out, int out_size, void* d_ws, size_t ws_size,
                              hipStream_t stream) {
    const float* x    = (const float*)d_in[0];   // [32768,1,28,28]
    const float* Wlin = (const float*)d_in[1];   // [784,196]
    const float* blin = (const float*)d_in[2];   // [784]
    float* out = (float*)d_out;                  // [32768,4,784]

    prep_w<<<(784 * 56 + 255) / 256, 256, 0, stream>>>(Wlin);
    prep_x<<<4096, 256, 0, stream>>>(x);

    dim3 grid(1024 * 7);                         // 7168 blocks, XCD-grouped swizzle
    dim3 block(256);
    patch_linear_mfma<<<grid, block, 0, stream>>>(blin, out);
}